// Round 5
// baseline (853.264 us; speedup 1.0000x reference)
//
#include <hip/hip_runtime.h>
#include <stdint.h>

#define NN 100000
#define NE 1600000
#define FDIM 128
#define NGRAPH 128
#define ODIM 16
#define NBKT 391                       // dst-buckets of 256 nodes
#define CAP 4608                       // fixed bucket capacity (mean 4092, sd 64)
#define SCHUNK 4096                    // edges per k_scat block
#define NSCAT ((NE + SCHUNK - 1) / SCHUNK)  // 391

typedef __attribute__((ext_vector_type(8))) short short8;
typedef __attribute__((ext_vector_type(8))) unsigned short ushort8;
typedef __attribute__((ext_vector_type(4))) float f32x4;

__device__ __forceinline__ float blo(unsigned int p) { return __uint_as_float(p << 16); }
__device__ __forceinline__ float bhi(unsigned int p) { return __uint_as_float(p & 0xffff0000u); }
__device__ __forceinline__ unsigned short f2b(float f) {
    unsigned int u = __float_as_uint(f);
    unsigned int r = (u + 0x7fffu + ((u >> 16) & 1u)) >> 16;
    return (unsigned short)r;
}
__device__ __forceinline__ unsigned int packbf(float lo, float hi) {
    return (unsigned int)f2b(lo) | ((unsigned int)f2b(hi) << 16);
}

// index load honoring runtime-detected width: w=1 -> int64 storage, w=0 -> int32
__device__ __forceinline__ int ld_idx(const int* __restrict__ p, long long i, int w) {
    return w ? p[2 * i] : p[i];
}

// ---------------- init: detect index width + init bucket cursors ----------------
__global__ void k_init(const int* __restrict__ ei, int* __restrict__ flag,
                       int* __restrict__ bcursor) {
    __shared__ int s;
    int t = threadIdx.x;
    if (t == 0) s = 0;
    __syncthreads();
    if (t < 64) {
        int v = ei[2 * t + 1];   // int64 inputs: odd int32 slots all 0
        if (v != 0) atomicOr(&s, 1);
    }
    if (t < NBKT) bcursor[t] = t * CAP;
    __syncthreads();
    if (t == 0) *flag = (s == 0) ? 1 : 0;
}

// ---------------- scatter edges into fixed-stride dst-buckets ----------------
// record = src (17 bits) | (dst & 255) << 17
__global__ void __launch_bounds__(512) k_scat(const int* __restrict__ ei,
                                              int* __restrict__ bcursor,
                                              unsigned int* __restrict__ rec,
                                              const int* __restrict__ flag) {
    __shared__ int hist[NBKT];
    __shared__ int gcur[NBKT];
    int t = threadIdx.x;
    for (int i = t; i < NBKT; i += 512) hist[i] = 0;
    __syncthreads();
    int w = *flag;
    long long e0 = (long long)blockIdx.x * SCHUNK;
    unsigned int myrec[8];
    int mybkt[8];
    #pragma unroll
    for (int j = 0; j < 8; ++j) {
        long long e = e0 + j * 512 + t;
        if (e < NE) {
            int s = ld_idx(ei, e, w);
            int d = ld_idx(ei, NE + e, w);
            mybkt[j] = d >> 8;
            myrec[j] = (unsigned int)s | ((unsigned int)(d & 255) << 17);
            atomicAdd(&hist[mybkt[j]], 1);
        } else mybkt[j] = -1;
    }
    __syncthreads();
    for (int i = t; i < NBKT; i += 512) {
        int c = hist[i];
        if (c) gcur[i] = atomicAdd(&bcursor[i], c);
    }
    __syncthreads();
    #pragma unroll
    for (int j = 0; j < 8; ++j) {
        int b = mybkt[j];
        if (b >= 0) {
            int p = atomicAdd(&gcur[b], 1);
            if (p < (b + 1) * CAP) rec[p] = myrec[j];   // overflow guard (~never)
        }
    }
}

// ---------------- per-bucket counting sort -> csr + offs + deg + dinv ----------------
__global__ void __launch_bounds__(256) k_bucket(const unsigned int* __restrict__ rec,
                                                const int* __restrict__ bcursor,
                                                int* __restrict__ csr,
                                                int* __restrict__ offs,
                                                int* __restrict__ deg,
                                                float* __restrict__ dinv) {
    __shared__ unsigned int rbuf[CAP];
    __shared__ int srcout[CAP];
    __shared__ int hist[256], scn[256], cur[256];
    int b = blockIdx.x, t = threadIdx.x;
    int base = b * CAP;
    int cnt = bcursor[b] - base;
    if (cnt > CAP) cnt = CAP;
    hist[t] = 0;
    __syncthreads();
    for (int j = t; j < cnt; j += 256) {
        unsigned int r = rec[base + j];
        rbuf[j] = r;
        atomicAdd(&hist[r >> 17], 1);
    }
    __syncthreads();
    int v = hist[t];
    scn[t] = v;
    __syncthreads();
    for (int o = 1; o < 256; o <<= 1) {
        int tv = (t >= o) ? scn[t - o] : 0;
        __syncthreads();
        scn[t] += tv;
        __syncthreads();
    }
    int excl = scn[t] - v;
    cur[t] = excl;
    int node = (b << 8) + t;
    if (node < NN) {
        offs[node] = base + excl;
        deg[node] = v;
        dinv[node] = rsqrtf((float)(v + 1));   // +1 = self loop
    }
    __syncthreads();
    for (int j = t; j < cnt; j += 256) {
        unsigned int r = rbuf[j];
        int p = atomicAdd(&cur[r >> 17], 1);
        srcout[p] = (int)(r & 0x1FFFFu);
    }
    __syncthreads();
    for (int j = t; j < cnt; j += 256) csr[base + j] = srcout[j];
}

// ---------------- graph start offsets (batch is sorted) ----------------
__global__ void k_starts(const int* __restrict__ batch, int* __restrict__ gstart,
                         const int* __restrict__ flag) {
    int i = blockIdx.x * 256 + threadIdx.x;
    if (i >= NN) return;
    int w = *flag;
    int b = ld_idx(batch, i, w);
    int prev = (i == 0) ? -1 : ld_idx(batch, i - 1, w);
    for (int g = prev + 1; g <= b; ++g) gstart[g] = i;
    if (i == NN - 1)
        for (int g = b + 1; g <= NGRAPH; ++g) gstart[g] = NN;
}

// ---------------- both weight transposes (fp32 -> bf16) ----------------
__global__ void k_transpose(const float* __restrict__ w1, const float* __restrict__ w2,
                            unsigned short* __restrict__ wt1, unsigned short* __restrict__ wt2) {
    int idx = blockIdx.x * 256 + threadIdx.x;   // 32768
    int which = idx >> 14, r = idx & 16383;
    int k = r >> 7, j = r & 127;
    const float* w = which ? w2 : w1;
    unsigned short* wt = which ? wt2 : wt1;
    wt[j * 128 + k] = f2b(w[k * 128 + j]);
}

// ---------------- GEMM: OUT[v][:] = bf16(dinv[v] * (X[v][:] @ W)) ----------------
#define LWS 136   // padded LDS row stride (bf16 elems)
template <bool BF16IN>
__global__ void __launch_bounds__(256) k_gemm(
    const void* __restrict__ Xv,            // [NN,128] fp32 or bf16
    const unsigned short* __restrict__ WT,  // [128,128] bf16, WT[j][k] = W[k][j]
    const float* __restrict__ dinv,
    unsigned short* __restrict__ OUT)       // [NN,128] bf16, scaled by dinv[row]
{
    __shared__ unsigned short lw[128 * LWS];
    int tid = threadIdx.x;
    for (int it = 0; it < 8; ++it) {
        int vidx = it * 256 + tid;
        int j = vidx >> 4, kc = vidx & 15;
        ushort8 v = *(const ushort8*)(WT + j * 128 + kc * 8);
        *(ushort8*)(&lw[j * LWS + kc * 8]) = v;
    }
    __syncthreads();

    int wave = tid >> 6, lane = tid & 63;
    int quad = lane >> 4, n16 = lane & 15;
    int row0 = (blockIdx.x * 4 + wave) * 16;
    if (row0 >= NN) return;   // NN % 16 == 0

    f32x4 acc[8];
    for (int ct = 0; ct < 8; ++ct) acc[ct] = (f32x4){0.f, 0.f, 0.f, 0.f};

    const int arow = row0 + n16;
    for (int kk = 0; kk < 4; ++kk) {
        short8 a;
        if (BF16IN) {
            a = *(const short8*)((const unsigned short*)Xv + (size_t)arow * 128 + kk * 32 + quad * 8);
        } else {
            const float* ap = (const float*)Xv + (size_t)arow * 128 + kk * 32 + quad * 8;
            float4 a01 = *(const float4*)(ap);
            float4 a23 = *(const float4*)(ap + 4);
            a[0] = (short)f2b(a01.x); a[1] = (short)f2b(a01.y);
            a[2] = (short)f2b(a01.z); a[3] = (short)f2b(a01.w);
            a[4] = (short)f2b(a23.x); a[5] = (short)f2b(a23.y);
            a[6] = (short)f2b(a23.z); a[7] = (short)f2b(a23.w);
        }
        for (int ct = 0; ct < 8; ++ct) {
            short8 b = *(const short8*)(&lw[(ct * 16 + n16) * LWS + kk * 32 + quad * 8]);
            acc[ct] = __builtin_amdgcn_mfma_f32_16x16x32_bf16(a, b, acc[ct], 0, 0, 0);
        }
    }
    // C/D layout: col = lane&15, row = quad*4 + reg
    for (int r = 0; r < 4; ++r) {
        int row = row0 + quad * 4 + r;
        float dv = dinv[row];
        for (int ct = 0; ct < 8; ++ct)
            OUT[(size_t)row * 128 + ct * 16 + n16] = f2b(acc[ct][r] * dv);
    }
}

// ---------------- aggregation: XCD-sliced gather ----------------
// Block b: feature slice = b & 7 (16 feats, 3.2 MB working set -> one XCD's L2),
// dst group = b >> 3 (4 dsts, one per wave). Per wave: lane = (edge slot e8, dword dw).
__global__ void __launch_bounds__(256) k_agg(
    const unsigned short* __restrict__ XWS,   // [NN,128] bf16, pre-scaled by dinv[row]
    const int* __restrict__ csr,
    const int* __restrict__ offs,
    const int* __restrict__ deg,
    const float* __restrict__ dinv,
    const float* __restrict__ bias,           // 128 fp32
    unsigned short* __restrict__ H)           // [NN,128] bf16
{
    int slice = blockIdx.x & 7;
    int grp   = blockIdx.x >> 3;
    int wave = threadIdx.x >> 6, lane = threadIdx.x & 63;
    int v = grp * 4 + wave;                    // NN % 4 == 0
    int e8 = lane >> 3, dw = lane & 7;
    int fb = slice * 16 + dw * 2;              // 2 features per dword
    int beg = offs[v], end = beg + deg[v];
    float a0 = 0.f, a1 = 0.f;
    if (e8 == 0) {   // self loop
        unsigned int q = *(const unsigned int*)(XWS + (size_t)v * FDIM + fb);
        a0 = blo(q); a1 = bhi(q);
    }
    for (int j = beg; j < end; j += 8) {
        int jj = j + e8;
        if (jj < end) {
            int idx = csr[jj];
            unsigned int q = *(const unsigned int*)(XWS + (size_t)idx * FDIM + fb);
            a0 += blo(q); a1 += bhi(q);
        }
    }
    a0 += __shfl_xor(a0, 8);  a1 += __shfl_xor(a1, 8);
    a0 += __shfl_xor(a0, 16); a1 += __shfl_xor(a1, 16);
    a0 += __shfl_xor(a0, 32); a1 += __shfl_xor(a1, 32);
    if (e8 == 0) {
        float dv = dinv[v];
        float2 bp = *(const float2*)(bias + fb);
        *(unsigned int*)(H + (size_t)v * FDIM + fb) =
            packbf(fmaxf(fmaf(a0, dv, bp.x), 0.f), fmaxf(fmaf(a1, dv, bp.y), 0.f));
    }
}

// ---------------- global mean pool ----------------
__global__ void __launch_bounds__(256) k_pool(
    const unsigned short* __restrict__ H, const int* __restrict__ gstart,
    float* __restrict__ pooled)
{
    __shared__ float red[512];
    int g = blockIdx.x;
    int t = threadIdx.x;
    int pair = t & 63;
    int seg = t >> 6;
    int beg = gstart[g], end = gstart[g + 1];
    float a0 = 0.f, a1 = 0.f;
    for (int i = beg + seg; i < end; i += 4) {
        unsigned int q = *(const unsigned int*)(H + (size_t)i * FDIM + 2 * pair);
        a0 += blo(q); a1 += bhi(q);
    }
    red[t] = a0; red[256 + t] = a1;
    __syncthreads();
    if (seg == 0) {
        a0 = red[t] + red[t + 64] + red[t + 128] + red[t + 192];
        a1 = red[256 + t] + red[256 + t + 64] + red[256 + t + 128] + red[256 + t + 192];
        float inv = 1.f / fmaxf((float)(end - beg), 1.f);
        pooled[g * FDIM + 2 * pair]     = a0 * inv;
        pooled[g * FDIM + 2 * pair + 1] = a1 * inv;
    }
}

// ---------------- classifier (fp32) ----------------
__global__ void k_cls(const float* __restrict__ pooled, const float* __restrict__ wc,
                      const float* __restrict__ bcb, float* __restrict__ out)
{
    int idx = blockIdx.x * 256 + threadIdx.x;
    if (idx >= NGRAPH * ODIM) return;
    int g = idx >> 4, o = idx & 15;
    float acc = bcb[o];
    for (int f = 0; f < FDIM; ++f)
        acc += pooled[g * FDIM + f] * wc[f * ODIM + o];
    out[idx] = acc;
}

extern "C" void kernel_launch(void* const* d_in, const int* in_sizes, int n_in,
                              void* d_out, int out_size, void* d_ws, size_t ws_size,
                              hipStream_t stream) {
    const float* x   = (const float*)d_in[0];
    const int* ei    = (const int*)d_in[1];
    const int* batch = (const int*)d_in[2];
    const float* w1  = (const float*)d_in[3];
    const float* b1  = (const float*)d_in[4];
    const float* w2  = (const float*)d_in[5];
    const float* b2  = (const float*)d_in[6];
    const float* wc  = (const float*)d_in[7];
    const float* bc  = (const float*)d_in[8];
    float* out = (float*)d_out;

    char* ws = (char*)d_ws;
    size_t off = 0;
    auto alloc = [&](size_t bytes) -> void* {
        off = (off + 255) & ~(size_t)255;
        void* p = ws + off;
        off += bytes;
        return p;
    };
    int*   flag    = (int*)alloc(4);
    int*   bcursor = (int*)alloc(NBKT * 4);
    int*   offs    = (int*)alloc(NN * 4);
    int*   deg     = (int*)alloc(NN * 4);
    float* dinv    = (float*)alloc(NN * 4);
    int*   gstart  = (int*)alloc((NGRAPH + 1) * 4);
    unsigned int* rec = (unsigned int*)alloc((size_t)NBKT * CAP * 4);
    int*   csr     = (int*)alloc((size_t)NBKT * CAP * 4);
    unsigned short* wt1 = (unsigned short*)alloc(128 * 128 * 2);
    unsigned short* wt2 = (unsigned short*)alloc(128 * 128 * 2);
    float* pooled  = (float*)alloc(NGRAPH * FDIM * 4);
    unsigned short* xws = (unsigned short*)alloc((size_t)NN * FDIM * 2);
    unsigned short* h   = (unsigned short*)alloc((size_t)NN * FDIM * 2);

    k_init<<<1, 512, 0, stream>>>(ei, flag, bcursor);
    k_scat<<<NSCAT, 512, 0, stream>>>(ei, bcursor, rec, flag);
    k_bucket<<<NBKT, 256, 0, stream>>>(rec, bcursor, csr, offs, deg, dinv);
    k_starts<<<(NN + 255) / 256, 256, 0, stream>>>(batch, gstart, flag);
    k_transpose<<<128, 256, 0, stream>>>(w1, w2, wt1, wt2);

    // layer 1
    k_gemm<false><<<(NN / 16 + 3) / 4, 256, 0, stream>>>(x, wt1, dinv, xws);
    k_agg<<<(NN / 4) * 8, 256, 0, stream>>>(xws, csr, offs, deg, dinv, b1, h);
    // layer 2
    k_gemm<true><<<(NN / 16 + 3) / 4, 256, 0, stream>>>(h, wt2, dinv, xws);
    k_agg<<<(NN / 4) * 8, 256, 0, stream>>>(xws, csr, offs, deg, dinv, b2, h);
    // pool + classify
    k_pool<<<NGRAPH, 256, 0, stream>>>(h, gstart, pooled);
    k_cls<<<8, 256, 0, stream>>>(pooled, wc, bc, out);
}

// Round 6
// 342.190 us; speedup vs baseline: 2.4935x; 2.4935x over previous
//
#include <hip/hip_runtime.h>
#include <stdint.h>

#define NN 100000
#define NE 1600000
#define FDIM 128
#define NGRAPH 128
#define ODIM 16
#define NBKT 391                       // dst-buckets of 256 nodes
#define CAP 4608                       // fixed bucket capacity (mean 4092, sd 64)
#define SCHUNK 4096                    // edges per k_scat block
#define NSCAT ((NE + SCHUNK - 1) / SCHUNK)  // 391
#define NSTARTB ((NN + 255) / 256)     // 391

typedef __attribute__((ext_vector_type(8))) short short8;
typedef __attribute__((ext_vector_type(8))) unsigned short ushort8;
typedef __attribute__((ext_vector_type(4))) float f32x4;

__device__ __forceinline__ float blo(unsigned int p) { return __uint_as_float(p << 16); }
__device__ __forceinline__ float bhi(unsigned int p) { return __uint_as_float(p & 0xffff0000u); }
__device__ __forceinline__ unsigned short f2b(float f) {
    unsigned int u = __float_as_uint(f);
    unsigned int r = (u + 0x7fffu + ((u >> 16) & 1u)) >> 16;
    return (unsigned short)r;
}
__device__ __forceinline__ unsigned int packbf(float lo, float hi) {
    return (unsigned int)f2b(lo) | ((unsigned int)f2b(hi) << 16);
}

// runtime index-width detect: int64 inputs (values < 2^31) have all-zero odd
// int32 slots; random int32 node ids can't have 64 consecutive zero odd slots.
__device__ __forceinline__ int detect_w(const int* __restrict__ ei) {
    int lane = threadIdx.x & 63;
    int v = ei[2 * lane + 1];
    return (__ballot(v != 0) == 0ULL) ? 1 : 0;
}
__device__ __forceinline__ int ld_idx(const int* __restrict__ p, long long i, int w) {
    return w ? p[2 * i] : p[i];
}

// ---------------- prep: weight transposes + graph starts + bucket cursors ----------------
__global__ void __launch_bounds__(256) k_prep(
    const float* __restrict__ w1, const float* __restrict__ w2,
    unsigned short* __restrict__ wt1, unsigned short* __restrict__ wt2,
    const int* __restrict__ ei, const int* __restrict__ batch,
    int* __restrict__ gstart, int* __restrict__ bcursor)
{
    int b = blockIdx.x, t = threadIdx.x;
    if (b < 128) {                       // both 128x128 transposes (fp32 -> bf16)
        int idx = b * 256 + t;           // 0..32767
        int which = idx >> 14, r = idx & 16383;
        int k = r >> 7, j = r & 127;
        const float* w = which ? w2 : w1;
        unsigned short* wt = which ? wt2 : wt1;
        wt[j * 128 + k] = f2b(w[k * 128 + j]);
    } else if (b < 128 + NSTARTB) {      // graph start offsets (batch sorted)
        int w = detect_w(ei);
        int i = (b - 128) * 256 + t;
        if (i < NN) {
            int bb = ld_idx(batch, i, w);
            int prev = (i == 0) ? -1 : ld_idx(batch, i - 1, w);
            for (int g = prev + 1; g <= bb; ++g) gstart[g] = i;
            if (i == NN - 1)
                for (int g = bb + 1; g <= NGRAPH; ++g) gstart[g] = NN;
        }
    } else {                             // bucket cursor init (2 blocks x 256)
        int i = (b - 128 - NSTARTB) * 256 + t;
        if (i < NBKT) bcursor[i] = i * CAP;
    }
}

// ---------------- scatter edges into fixed-stride dst-buckets ----------------
// record = src (17 bits) | (dst & 255) << 17
__global__ void __launch_bounds__(512) k_scat(const int* __restrict__ ei,
                                              int* __restrict__ bcursor,
                                              unsigned int* __restrict__ rec) {
    __shared__ int hist[NBKT];
    __shared__ int gcur[NBKT];
    int t = threadIdx.x;
    int w = detect_w(ei);
    for (int i = t; i < NBKT; i += 512) hist[i] = 0;
    __syncthreads();
    long long e0 = (long long)blockIdx.x * SCHUNK;
    unsigned int myrec[8];
    int mybkt[8];
    #pragma unroll
    for (int j = 0; j < 8; ++j) {
        long long e = e0 + j * 512 + t;
        if (e < NE) {
            int s = ld_idx(ei, e, w);
            int d = ld_idx(ei, NE + e, w);
            mybkt[j] = d >> 8;
            myrec[j] = (unsigned int)s | ((unsigned int)(d & 255) << 17);
            atomicAdd(&hist[mybkt[j]], 1);
        } else mybkt[j] = -1;
    }
    __syncthreads();
    for (int i = t; i < NBKT; i += 512) {
        int c = hist[i];
        if (c) gcur[i] = atomicAdd(&bcursor[i], c);
    }
    __syncthreads();
    #pragma unroll
    for (int j = 0; j < 8; ++j) {
        int b = mybkt[j];
        if (b >= 0) {
            int p = atomicAdd(&gcur[b], 1);
            if (p < (b + 1) * CAP) rec[p] = myrec[j];   // overflow guard (~never)
        }
    }
}

// ---------------- per-bucket counting sort -> csr + offs + deg + dinv ----------------
__global__ void __launch_bounds__(256) k_bucket(const unsigned int* __restrict__ rec,
                                                const int* __restrict__ bcursor,
                                                int* __restrict__ csr,
                                                int* __restrict__ offs,
                                                int* __restrict__ deg,
                                                float* __restrict__ dinv) {
    __shared__ unsigned int rbuf[CAP];
    __shared__ int srcout[CAP];
    __shared__ int hist[256], scn[256], cur[256];
    int b = blockIdx.x, t = threadIdx.x;
    int base = b * CAP;
    int cnt = bcursor[b] - base;
    if (cnt > CAP) cnt = CAP;
    hist[t] = 0;
    __syncthreads();
    for (int j = t; j < cnt; j += 256) {
        unsigned int r = rec[base + j];
        rbuf[j] = r;
        atomicAdd(&hist[r >> 17], 1);
    }
    __syncthreads();
    int v = hist[t];
    scn[t] = v;
    __syncthreads();
    for (int o = 1; o < 256; o <<= 1) {
        int tv = (t >= o) ? scn[t - o] : 0;
        __syncthreads();
        scn[t] += tv;
        __syncthreads();
    }
    int excl = scn[t] - v;
    cur[t] = excl;
    int node = (b << 8) + t;
    if (node < NN) {
        offs[node] = base + excl;
        deg[node] = v;
        dinv[node] = rsqrtf((float)(v + 1));   // +1 = self loop
    }
    __syncthreads();
    for (int j = t; j < cnt; j += 256) {
        unsigned int r = rbuf[j];
        int p = atomicAdd(&cur[r >> 17], 1);
        srcout[p] = (int)(r & 0x1FFFFu);
    }
    __syncthreads();
    for (int j = t; j < cnt; j += 256) csr[base + j] = srcout[j];
}

// ---------------- GEMM: OUT[v][:] = bf16(dinv[v] * (X[v][:] @ W)) ----------------
#define LWS 136   // padded LDS row stride (bf16 elems)
template <bool BF16IN>
__global__ void __launch_bounds__(256) k_gemm(
    const void* __restrict__ Xv,            // [NN,128] fp32 or bf16
    const unsigned short* __restrict__ WT,  // [128,128] bf16, WT[j][k] = W[k][j]
    const float* __restrict__ dinv,
    unsigned short* __restrict__ OUT)       // [NN,128] bf16, scaled by dinv[row]
{
    __shared__ unsigned short lw[128 * LWS];
    int tid = threadIdx.x;
    for (int it = 0; it < 8; ++it) {
        int vidx = it * 256 + tid;
        int j = vidx >> 4, kc = vidx & 15;
        ushort8 v = *(const ushort8*)(WT + j * 128 + kc * 8);
        *(ushort8*)(&lw[j * LWS + kc * 8]) = v;
    }
    __syncthreads();

    int wave = tid >> 6, lane = tid & 63;
    int quad = lane >> 4, n16 = lane & 15;
    int row0 = (blockIdx.x * 4 + wave) * 16;
    if (row0 >= NN) return;   // NN % 16 == 0

    f32x4 acc[8];
    for (int ct = 0; ct < 8; ++ct) acc[ct] = (f32x4){0.f, 0.f, 0.f, 0.f};

    const int arow = row0 + n16;
    for (int kk = 0; kk < 4; ++kk) {
        short8 a;
        if (BF16IN) {
            a = *(const short8*)((const unsigned short*)Xv + (size_t)arow * 128 + kk * 32 + quad * 8);
        } else {
            const float* ap = (const float*)Xv + (size_t)arow * 128 + kk * 32 + quad * 8;
            float4 a01 = *(const float4*)(ap);
            float4 a23 = *(const float4*)(ap + 4);
            a[0] = (short)f2b(a01.x); a[1] = (short)f2b(a01.y);
            a[2] = (short)f2b(a01.z); a[3] = (short)f2b(a01.w);
            a[4] = (short)f2b(a23.x); a[5] = (short)f2b(a23.y);
            a[6] = (short)f2b(a23.z); a[7] = (short)f2b(a23.w);
        }
        for (int ct = 0; ct < 8; ++ct) {
            short8 b = *(const short8*)(&lw[(ct * 16 + n16) * LWS + kk * 32 + quad * 8]);
            acc[ct] = __builtin_amdgcn_mfma_f32_16x16x32_bf16(a, b, acc[ct], 0, 0, 0);
        }
    }
    // C/D layout: col = lane&15, row = quad*4 + reg
    for (int r = 0; r < 4; ++r) {
        int row = row0 + quad * 4 + r;
        float dv = dinv[row];
        for (int ct = 0; ct < 8; ++ct)
            OUT[(size_t)row * 128 + ct * 16 + n16] = f2b(acc[ct][r] * dv);
    }
}

// ---------------- aggregation: 8 edges in flight per lane-group, xor-shuffle reduce ----
__global__ void __launch_bounds__(256) k_agg(
    const unsigned short* __restrict__ XWS,   // [NN,128] bf16, pre-scaled by dinv[row]
    const int* __restrict__ csr,
    const int* __restrict__ offs,
    const int* __restrict__ deg,
    const float* __restrict__ dinv,
    const float* __restrict__ bias,           // 128 fp32
    unsigned short* __restrict__ H)           // [NN,128] bf16
{
    int wave = threadIdx.x >> 6, lane = threadIdx.x & 63;
    int v = blockIdx.x * 4 + wave;             // NN % 4 == 0
    int g = lane >> 4, f = lane & 15;          // edge slot, feature chunk (8 feats)
    int beg = offs[v], end = beg + deg[v];
    float a[8];
    if (g == 0) {   // self loop
        uint4 q = *(const uint4*)(XWS + (size_t)v * FDIM + f * 8);
        a[0] = blo(q.x); a[1] = bhi(q.x); a[2] = blo(q.y); a[3] = bhi(q.y);
        a[4] = blo(q.z); a[5] = bhi(q.z); a[6] = blo(q.w); a[7] = bhi(q.w);
    } else {
        #pragma unroll
        for (int i = 0; i < 8; ++i) a[i] = 0.f;
    }
    int j = beg;
    for (; j + 8 <= end; j += 8) {             // two independent gathers in flight
        int i0 = csr[j + g], i1 = csr[j + 4 + g];
        uint4 q0 = *(const uint4*)(XWS + (size_t)i0 * FDIM + f * 8);
        uint4 q1 = *(const uint4*)(XWS + (size_t)i1 * FDIM + f * 8);
        a[0] += blo(q0.x); a[1] += bhi(q0.x); a[2] += blo(q0.y); a[3] += bhi(q0.y);
        a[4] += blo(q0.z); a[5] += bhi(q0.z); a[6] += blo(q0.w); a[7] += bhi(q0.w);
        a[0] += blo(q1.x); a[1] += bhi(q1.x); a[2] += blo(q1.y); a[3] += bhi(q1.y);
        a[4] += blo(q1.z); a[5] += bhi(q1.z); a[6] += blo(q1.w); a[7] += bhi(q1.w);
    }
    if (j + 4 <= end) {
        int idx = csr[j + g];
        uint4 q = *(const uint4*)(XWS + (size_t)idx * FDIM + f * 8);
        a[0] += blo(q.x); a[1] += bhi(q.x); a[2] += blo(q.y); a[3] += bhi(q.y);
        a[4] += blo(q.z); a[5] += bhi(q.z); a[6] += blo(q.w); a[7] += bhi(q.w);
        j += 4;
    }
    int rem = end - j;
    if (g < rem) {
        int idx = csr[j + g];
        uint4 q = *(const uint4*)(XWS + (size_t)idx * FDIM + f * 8);
        a[0] += blo(q.x); a[1] += bhi(q.x); a[2] += blo(q.y); a[3] += bhi(q.y);
        a[4] += blo(q.z); a[5] += bhi(q.z); a[6] += blo(q.w); a[7] += bhi(q.w);
    }
    #pragma unroll
    for (int i = 0; i < 8; ++i) {
        a[i] += __shfl_xor(a[i], 16);
        a[i] += __shfl_xor(a[i], 32);
    }
    if (g == 0) {
        float dv = dinv[v];
        float4 b0 = *(const float4*)(bias + f * 8);
        float4 b1 = *(const float4*)(bias + f * 8 + 4);
        uint4 o;
        o.x = packbf(fmaxf(fmaf(a[0], dv, b0.x), 0.f), fmaxf(fmaf(a[1], dv, b0.y), 0.f));
        o.y = packbf(fmaxf(fmaf(a[2], dv, b0.z), 0.f), fmaxf(fmaf(a[3], dv, b0.w), 0.f));
        o.z = packbf(fmaxf(fmaf(a[4], dv, b1.x), 0.f), fmaxf(fmaf(a[5], dv, b1.y), 0.f));
        o.w = packbf(fmaxf(fmaf(a[6], dv, b1.z), 0.f), fmaxf(fmaf(a[7], dv, b1.w), 0.f));
        *(uint4*)(H + (size_t)v * FDIM + f * 8) = o;
    }
}

// ---------------- fused global mean pool + classifier ----------------
__global__ void __launch_bounds__(256) k_poolcls(
    const unsigned short* __restrict__ H, const int* __restrict__ gstart,
    const float* __restrict__ wc, const float* __restrict__ bc,
    float* __restrict__ out)
{
    __shared__ float red[512];
    __shared__ float pl[FDIM];
    int g = blockIdx.x;
    int t = threadIdx.x;
    int pair = t & 63;
    int seg = t >> 6;
    int beg = gstart[g], end = gstart[g + 1];
    float a0 = 0.f, a1 = 0.f;
    for (int i = beg + seg; i < end; i += 4) {
        unsigned int q = *(const unsigned int*)(H + (size_t)i * FDIM + 2 * pair);
        a0 += blo(q); a1 += bhi(q);
    }
    red[t] = a0; red[256 + t] = a1;
    __syncthreads();
    if (seg == 0) {
        a0 = red[t] + red[t + 64] + red[t + 128] + red[t + 192];
        a1 = red[256 + t] + red[256 + t + 64] + red[256 + t + 128] + red[256 + t + 192];
        float inv = 1.f / fmaxf((float)(end - beg), 1.f);
        pl[2 * pair] = a0 * inv;
        pl[2 * pair + 1] = a1 * inv;
    }
    __syncthreads();
    // classifier: o = t&15, 16 feature-segments of 8, reduce via LDS
    int o = t & 15, fs = t >> 4;
    float acc = 0.f;
    #pragma unroll
    for (int k = 0; k < 8; ++k)
        acc += pl[fs * 8 + k] * wc[(fs * 8 + k) * ODIM + o];
    red[t] = acc;
    __syncthreads();
    if (t < 16) {
        float s = bc[t];
        #pragma unroll
        for (int k = 0; k < 16; ++k) s += red[k * 16 + t];
        out[g * ODIM + t] = s;
    }
}

extern "C" void kernel_launch(void* const* d_in, const int* in_sizes, int n_in,
                              void* d_out, int out_size, void* d_ws, size_t ws_size,
                              hipStream_t stream) {
    const float* x   = (const float*)d_in[0];
    const int* ei    = (const int*)d_in[1];
    const int* batch = (const int*)d_in[2];
    const float* w1  = (const float*)d_in[3];
    const float* b1  = (const float*)d_in[4];
    const float* w2  = (const float*)d_in[5];
    const float* b2  = (const float*)d_in[6];
    const float* wc  = (const float*)d_in[7];
    const float* bc  = (const float*)d_in[8];
    float* out = (float*)d_out;

    char* ws = (char*)d_ws;
    size_t off = 0;
    auto alloc = [&](size_t bytes) -> void* {
        off = (off + 255) & ~(size_t)255;
        void* p = ws + off;
        off += bytes;
        return p;
    };
    int*   bcursor = (int*)alloc(NBKT * 4);
    int*   offs    = (int*)alloc(NN * 4);
    int*   deg     = (int*)alloc(NN * 4);
    float* dinv    = (float*)alloc(NN * 4);
    int*   gstart  = (int*)alloc((NGRAPH + 1) * 4);
    unsigned int* rec = (unsigned int*)alloc((size_t)NBKT * CAP * 4);
    int*   csr     = (int*)alloc((size_t)NBKT * CAP * 4);
    unsigned short* wt1 = (unsigned short*)alloc(128 * 128 * 2);
    unsigned short* wt2 = (unsigned short*)alloc(128 * 128 * 2);
    unsigned short* xws = (unsigned short*)alloc((size_t)NN * FDIM * 2);
    unsigned short* h   = (unsigned short*)alloc((size_t)NN * FDIM * 2);

    k_prep<<<128 + NSTARTB + 2, 256, 0, stream>>>(w1, w2, wt1, wt2, ei, batch, gstart, bcursor);
    k_scat<<<NSCAT, 512, 0, stream>>>(ei, bcursor, rec);
    k_bucket<<<NBKT, 256, 0, stream>>>(rec, bcursor, csr, offs, deg, dinv);

    // layer 1
    k_gemm<false><<<(NN / 16 + 3) / 4, 256, 0, stream>>>(x, wt1, dinv, xws);
    k_agg<<<NN / 4, 256, 0, stream>>>(xws, csr, offs, deg, dinv, b1, h);
    // layer 2
    k_gemm<true><<<(NN / 16 + 3) / 4, 256, 0, stream>>>(h, wt2, dinv, xws);
    k_agg<<<NN / 4, 256, 0, stream>>>(xws, csr, offs, deg, dinv, b2, h);
    // pool + classify (fused)
    k_poolcls<<<NGRAPH, 256, 0, stream>>>(h, gstart, wc, bc, out);
}

// Round 7
// 333.395 us; speedup vs baseline: 2.5593x; 1.0264x over previous
//
#include <hip/hip_runtime.h>
#include <stdint.h>

#define NN 100000
#define NE 1600000
#define FDIM 128
#define NGRAPH 128
#define ODIM 16
#define NBKT 391                       // dst-buckets of 256 nodes
#define CAP 4608                       // fixed bucket capacity (mean 4092, sd 64)
#define SCHUNK 4096                    // edges per k_scat block
#define NSCAT ((NE + SCHUNK - 1) / SCHUNK)  // 391
#define NSTARTB ((NN + 255) / 256)     // 391

typedef __attribute__((ext_vector_type(8))) short short8;
typedef __attribute__((ext_vector_type(8))) unsigned short ushort8;
typedef __attribute__((ext_vector_type(4))) float f32x4;

__device__ __forceinline__ float blo(unsigned int p) { return __uint_as_float(p << 16); }
__device__ __forceinline__ float bhi(unsigned int p) { return __uint_as_float(p & 0xffff0000u); }
__device__ __forceinline__ unsigned short f2b(float f) {
    unsigned int u = __float_as_uint(f);
    unsigned int r = (u + 0x7fffu + ((u >> 16) & 1u)) >> 16;
    return (unsigned short)r;
}
__device__ __forceinline__ unsigned int packbf(float lo, float hi) {
    return (unsigned int)f2b(lo) | ((unsigned int)f2b(hi) << 16);
}

// runtime index-width detect: int64 inputs (values < 2^31) have all-zero odd
// int32 slots; random int32 node ids can't have 64 consecutive zero odd slots.
__device__ __forceinline__ int detect_w(const int* __restrict__ ei) {
    int lane = threadIdx.x & 63;
    int v = ei[2 * lane + 1];
    return (__ballot(v != 0) == 0ULL) ? 1 : 0;
}
__device__ __forceinline__ int ld_idx(const int* __restrict__ p, long long i, int w) {
    return w ? p[2 * i] : p[i];
}

// ---------------- prep: transposes + graph starts + cursors + zero-row ----------------
__global__ void __launch_bounds__(256) k_prep(
    const float* __restrict__ w1, const float* __restrict__ w2,
    unsigned short* __restrict__ wt1, unsigned short* __restrict__ wt2,
    const int* __restrict__ ei, const int* __restrict__ batch,
    int* __restrict__ gstart, int* __restrict__ bcursor,
    unsigned short* __restrict__ xws)
{
    int b = blockIdx.x, t = threadIdx.x;
    if (b < 128) {                       // both 128x128 transposes (fp32 -> bf16)
        int idx = b * 256 + t;           // 0..32767
        int which = idx >> 14, r = idx & 16383;
        int k = r >> 7, j = r & 127;
        const float* w = which ? w2 : w1;
        unsigned short* wt = which ? wt2 : wt1;
        wt[j * 128 + k] = f2b(w[k * 128 + j]);
    } else if (b < 128 + NSTARTB) {      // graph start offsets (batch sorted)
        int w = detect_w(ei);
        int i = (b - 128) * 256 + t;
        if (i < NN) {
            int bb = ld_idx(batch, i, w);
            int prev = (i == 0) ? -1 : ld_idx(batch, i - 1, w);
            for (int g = prev + 1; g <= bb; ++g) gstart[g] = i;
            if (i == NN - 1)
                for (int g = bb + 1; g <= NGRAPH; ++g) gstart[g] = NN;
        }
    } else {                             // cursor init + zero row NN of xws
        int i = (b - 128 - NSTARTB) * 256 + t;
        if (i < NBKT) bcursor[i] = i * CAP;
        if (b == 128 + NSTARTB && t < FDIM) xws[(size_t)NN * FDIM + t] = 0;
    }
}

// ---------------- scatter edges into fixed-stride dst-buckets ----------------
// record = src (17 bits) | (dst & 255) << 17
__global__ void __launch_bounds__(512) k_scat(const int* __restrict__ ei,
                                              int* __restrict__ bcursor,
                                              unsigned int* __restrict__ rec) {
    __shared__ int hist[NBKT];
    __shared__ int gcur[NBKT];
    int t = threadIdx.x;
    int w = detect_w(ei);
    for (int i = t; i < NBKT; i += 512) hist[i] = 0;
    __syncthreads();
    long long e0 = (long long)blockIdx.x * SCHUNK;
    unsigned int myrec[8];
    int mybkt[8];
    #pragma unroll
    for (int j = 0; j < 8; ++j) {
        long long e = e0 + j * 512 + t;
        if (e < NE) {
            int s = ld_idx(ei, e, w);
            int d = ld_idx(ei, NE + e, w);
            mybkt[j] = d >> 8;
            myrec[j] = (unsigned int)s | ((unsigned int)(d & 255) << 17);
            atomicAdd(&hist[mybkt[j]], 1);
        } else mybkt[j] = -1;
    }
    __syncthreads();
    for (int i = t; i < NBKT; i += 512) {
        int c = hist[i];
        if (c) gcur[i] = atomicAdd(&bcursor[i], c);
    }
    __syncthreads();
    #pragma unroll
    for (int j = 0; j < 8; ++j) {
        int b = mybkt[j];
        if (b >= 0) {
            int p = atomicAdd(&gcur[b], 1);
            if (p < (b + 1) * CAP) rec[p] = myrec[j];   // overflow guard (~never)
        }
    }
}

// ---------------- per-bucket counting sort -> csr + offs + deg + dinv ----------------
__global__ void __launch_bounds__(256) k_bucket(const unsigned int* __restrict__ rec,
                                                const int* __restrict__ bcursor,
                                                int* __restrict__ csr,
                                                int* __restrict__ offs,
                                                int* __restrict__ deg,
                                                float* __restrict__ dinv) {
    __shared__ unsigned int rbuf[CAP];
    __shared__ int srcout[CAP];
    __shared__ int hist[256], scn[256], cur[256];
    int b = blockIdx.x, t = threadIdx.x;
    int base = b * CAP;
    int cnt = bcursor[b] - base;
    if (cnt > CAP) cnt = CAP;
    hist[t] = 0;
    __syncthreads();
    for (int j = t; j < cnt; j += 256) {
        unsigned int r = rec[base + j];
        rbuf[j] = r;
        atomicAdd(&hist[r >> 17], 1);
    }
    __syncthreads();
    int v = hist[t];
    scn[t] = v;
    __syncthreads();
    for (int o = 1; o < 256; o <<= 1) {
        int tv = (t >= o) ? scn[t - o] : 0;
        __syncthreads();
        scn[t] += tv;
        __syncthreads();
    }
    int excl = scn[t] - v;
    cur[t] = excl;
    int node = (b << 8) + t;
    if (node < NN) {
        offs[node] = base + excl;
        deg[node] = v;
        dinv[node] = rsqrtf((float)(v + 1));   // +1 = self loop
    }
    __syncthreads();
    for (int j = t; j < cnt; j += 256) {
        unsigned int r = rbuf[j];
        int p = atomicAdd(&cur[r >> 17], 1);
        srcout[p] = (int)(r & 0x1FFFFu);
    }
    __syncthreads();
    for (int j = t; j < cnt; j += 256) csr[base + j] = srcout[j];
}

// ---------------- GEMM: OUT[v][:] = bf16(dinv[v] * (X[v][:] @ W)) ----------------
#define LWS 136   // padded LDS row stride (bf16 elems)
template <bool BF16IN>
__global__ void __launch_bounds__(256) k_gemm(
    const void* __restrict__ Xv,            // [NN,128] fp32 or bf16
    const unsigned short* __restrict__ WT,  // [128,128] bf16, WT[j][k] = W[k][j]
    const float* __restrict__ dinv,
    unsigned short* __restrict__ OUT)       // [NN,128] bf16, scaled by dinv[row]
{
    __shared__ unsigned short lw[128 * LWS];
    int tid = threadIdx.x;
    for (int it = 0; it < 8; ++it) {
        int vidx = it * 256 + tid;
        int j = vidx >> 4, kc = vidx & 15;
        ushort8 v = *(const ushort8*)(WT + j * 128 + kc * 8);
        *(ushort8*)(&lw[j * LWS + kc * 8]) = v;
    }
    __syncthreads();

    int wave = tid >> 6, lane = tid & 63;
    int quad = lane >> 4, n16 = lane & 15;
    int row0 = (blockIdx.x * 4 + wave) * 16;
    if (row0 >= NN) return;   // NN % 16 == 0

    f32x4 acc[8];
    for (int ct = 0; ct < 8; ++ct) acc[ct] = (f32x4){0.f, 0.f, 0.f, 0.f};

    const int arow = row0 + n16;
    for (int kk = 0; kk < 4; ++kk) {
        short8 a;
        if (BF16IN) {
            a = *(const short8*)((const unsigned short*)Xv + (size_t)arow * 128 + kk * 32 + quad * 8);
        } else {
            const float* ap = (const float*)Xv + (size_t)arow * 128 + kk * 32 + quad * 8;
            float4 a01 = *(const float4*)(ap);
            float4 a23 = *(const float4*)(ap + 4);
            a[0] = (short)f2b(a01.x); a[1] = (short)f2b(a01.y);
            a[2] = (short)f2b(a01.z); a[3] = (short)f2b(a01.w);
            a[4] = (short)f2b(a23.x); a[5] = (short)f2b(a23.y);
            a[6] = (short)f2b(a23.z); a[7] = (short)f2b(a23.w);
        }
        for (int ct = 0; ct < 8; ++ct) {
            short8 b = *(const short8*)(&lw[(ct * 16 + n16) * LWS + kk * 32 + quad * 8]);
            acc[ct] = __builtin_amdgcn_mfma_f32_16x16x32_bf16(a, b, acc[ct], 0, 0, 0);
        }
    }
    // C/D layout: col = lane&15, row = quad*4 + reg
    for (int r = 0; r < 4; ++r) {
        int row = row0 + quad * 4 + r;
        float dv = dinv[row];
        for (int ct = 0; ct < 8; ++ct)
            OUT[(size_t)row * 128 + ct * 16 + n16] = f2b(acc[ct][r] * dv);
    }
}

// ---------------- aggregation: 16 edges in flight per wave, branch-free ----------------
// Lane = (edge slot g 0..3, feature chunk f 0..15). Padded slots gather xws row NN (zeros).
__global__ void __launch_bounds__(256) k_agg(
    const unsigned short* __restrict__ XWS,   // [NN+1,128] bf16, row NN = zeros
    const int* __restrict__ csr,
    const int* __restrict__ offs,
    const int* __restrict__ deg,
    const float* __restrict__ dinv,
    const float* __restrict__ bias,           // 128 fp32
    unsigned short* __restrict__ H)           // [NN,128] bf16
{
    int wave = threadIdx.x >> 6, lane = threadIdx.x & 63;
    int v = blockIdx.x * 4 + wave;             // NN % 4 == 0
    int g = lane >> 4, f = lane & 15;          // edge slot, feature chunk (8 feats)
    int beg = offs[v], end = beg + deg[v];
    float a[8];
    {   // self loop
        uint4 q = *(const uint4*)(XWS + (size_t)v * FDIM + f * 8);
        float m = (g == 0) ? 1.f : 0.f;
        a[0] = m * blo(q.x); a[1] = m * bhi(q.x); a[2] = m * blo(q.y); a[3] = m * bhi(q.y);
        a[4] = m * blo(q.z); a[5] = m * bhi(q.z); a[6] = m * blo(q.w); a[7] = m * bhi(q.w);
    }
    int e1 = end - 1;
    for (int j = beg; j < end; j += 16) {
        int j0 = j + g, j1 = j + 4 + g, j2 = j + 8 + g, j3 = j + 12 + g;
        int i0 = csr[j0 < end ? j0 : e1]; i0 = (j0 < end) ? i0 : NN;
        int i1 = csr[j1 < end ? j1 : e1]; i1 = (j1 < end) ? i1 : NN;
        int i2 = csr[j2 < end ? j2 : e1]; i2 = (j2 < end) ? i2 : NN;
        int i3 = csr[j3 < end ? j3 : e1]; i3 = (j3 < end) ? i3 : NN;
        uint4 q0 = *(const uint4*)(XWS + (size_t)i0 * FDIM + f * 8);
        uint4 q1 = *(const uint4*)(XWS + (size_t)i1 * FDIM + f * 8);
        uint4 q2 = *(const uint4*)(XWS + (size_t)i2 * FDIM + f * 8);
        uint4 q3 = *(const uint4*)(XWS + (size_t)i3 * FDIM + f * 8);
        a[0] += blo(q0.x); a[1] += bhi(q0.x); a[2] += blo(q0.y); a[3] += bhi(q0.y);
        a[4] += blo(q0.z); a[5] += bhi(q0.z); a[6] += blo(q0.w); a[7] += bhi(q0.w);
        a[0] += blo(q1.x); a[1] += bhi(q1.x); a[2] += blo(q1.y); a[3] += bhi(q1.y);
        a[4] += blo(q1.z); a[5] += bhi(q1.z); a[6] += blo(q1.w); a[7] += bhi(q1.w);
        a[0] += blo(q2.x); a[1] += bhi(q2.x); a[2] += blo(q2.y); a[3] += bhi(q2.y);
        a[4] += blo(q2.z); a[5] += bhi(q2.z); a[6] += blo(q2.w); a[7] += bhi(q2.w);
        a[0] += blo(q3.x); a[1] += bhi(q3.x); a[2] += blo(q3.y); a[3] += bhi(q3.y);
        a[4] += blo(q3.z); a[5] += bhi(q3.z); a[6] += blo(q3.w); a[7] += bhi(q3.w);
    }
    #pragma unroll
    for (int i = 0; i < 8; ++i) {
        a[i] += __shfl_xor(a[i], 16);
        a[i] += __shfl_xor(a[i], 32);
    }
    if (g == 0) {
        float dv = dinv[v];
        float4 b0 = *(const float4*)(bias + f * 8);
        float4 b1 = *(const float4*)(bias + f * 8 + 4);
        uint4 o;
        o.x = packbf(fmaxf(fmaf(a[0], dv, b0.x), 0.f), fmaxf(fmaf(a[1], dv, b0.y), 0.f));
        o.y = packbf(fmaxf(fmaf(a[2], dv, b0.z), 0.f), fmaxf(fmaf(a[3], dv, b0.w), 0.f));
        o.z = packbf(fmaxf(fmaf(a[4], dv, b1.x), 0.f), fmaxf(fmaf(a[5], dv, b1.y), 0.f));
        o.w = packbf(fmaxf(fmaf(a[6], dv, b1.z), 0.f), fmaxf(fmaf(a[7], dv, b1.w), 0.f));
        *(uint4*)(H + (size_t)v * FDIM + f * 8) = o;
    }
}

// ---------------- fused global mean pool + classifier ----------------
__global__ void __launch_bounds__(256) k_poolcls(
    const unsigned short* __restrict__ H, const int* __restrict__ gstart,
    const float* __restrict__ wc, const float* __restrict__ bc,
    float* __restrict__ out)
{
    __shared__ float red[512];
    __shared__ float pl[FDIM];
    int g = blockIdx.x;
    int t = threadIdx.x;
    int pair = t & 63;
    int seg = t >> 6;
    int beg = gstart[g], end = gstart[g + 1];
    float a0 = 0.f, a1 = 0.f;
    for (int i = beg + seg; i < end; i += 4) {
        unsigned int q = *(const unsigned int*)(H + (size_t)i * FDIM + 2 * pair);
        a0 += blo(q); a1 += bhi(q);
    }
    red[t] = a0; red[256 + t] = a1;
    __syncthreads();
    if (seg == 0) {
        a0 = red[t] + red[t + 64] + red[t + 128] + red[t + 192];
        a1 = red[256 + t] + red[256 + t + 64] + red[256 + t + 128] + red[256 + t + 192];
        float inv = 1.f / fmaxf((float)(end - beg), 1.f);
        pl[2 * pair] = a0 * inv;
        pl[2 * pair + 1] = a1 * inv;
    }
    __syncthreads();
    int o = t & 15, fs = t >> 4;
    float acc = 0.f;
    #pragma unroll
    for (int k = 0; k < 8; ++k)
        acc += pl[fs * 8 + k] * wc[(fs * 8 + k) * ODIM + o];
    red[t] = acc;
    __syncthreads();
    if (t < 16) {
        float s = bc[t];
        #pragma unroll
        for (int k = 0; k < 16; ++k) s += red[k * 16 + t];
        out[g * ODIM + t] = s;
    }
}

extern "C" void kernel_launch(void* const* d_in, const int* in_sizes, int n_in,
                              void* d_out, int out_size, void* d_ws, size_t ws_size,
                              hipStream_t stream) {
    const float* x   = (const float*)d_in[0];
    const int* ei    = (const int*)d_in[1];
    const int* batch = (const int*)d_in[2];
    const float* w1  = (const float*)d_in[3];
    const float* b1  = (const float*)d_in[4];
    const float* w2  = (const float*)d_in[5];
    const float* b2  = (const float*)d_in[6];
    const float* wc  = (const float*)d_in[7];
    const float* bc  = (const float*)d_in[8];
    float* out = (float*)d_out;

    char* ws = (char*)d_ws;
    size_t off = 0;
    auto alloc = [&](size_t bytes) -> void* {
        off = (off + 255) & ~(size_t)255;
        void* p = ws + off;
        off += bytes;
        return p;
    };
    int*   bcursor = (int*)alloc(NBKT * 4);
    int*   offs    = (int*)alloc(NN * 4);
    int*   deg     = (int*)alloc(NN * 4);
    float* dinv    = (float*)alloc(NN * 4);
    int*   gstart  = (int*)alloc((NGRAPH + 1) * 4);
    unsigned int* rec = (unsigned int*)alloc((size_t)NBKT * CAP * 4);
    int*   csr     = (int*)alloc((size_t)NBKT * CAP * 4 + 256);   // +tail slack
    unsigned short* wt1 = (unsigned short*)alloc(128 * 128 * 2);
    unsigned short* wt2 = (unsigned short*)alloc(128 * 128 * 2);
    unsigned short* xws = (unsigned short*)alloc((size_t)(NN + 1) * FDIM * 2);  // +zero row
    unsigned short* h   = (unsigned short*)alloc((size_t)NN * FDIM * 2);

    k_prep<<<128 + NSTARTB + 2, 256, 0, stream>>>(w1, w2, wt1, wt2, ei, batch, gstart, bcursor, xws);
    k_scat<<<NSCAT, 512, 0, stream>>>(ei, bcursor, rec);
    k_bucket<<<NBKT, 256, 0, stream>>>(rec, bcursor, csr, offs, deg, dinv);

    // layer 1
    k_gemm<false><<<(NN / 16 + 3) / 4, 256, 0, stream>>>(x, wt1, dinv, xws);
    k_agg<<<NN / 4, 256, 0, stream>>>(xws, csr, offs, deg, dinv, b1, h);
    // layer 2
    k_gemm<true><<<(NN / 16 + 3) / 4, 256, 0, stream>>>(h, wt2, dinv, xws);
    k_agg<<<NN / 4, 256, 0, stream>>>(xws, csr, offs, deg, dinv, b2, h);
    // pool + classify (fused)
    k_poolcls<<<NGRAPH, 256, 0, stream>>>(h, gstart, wc, bc, out);
}

// Round 8
// 333.217 us; speedup vs baseline: 2.5607x; 1.0005x over previous
//
#include <hip/hip_runtime.h>
#include <stdint.h>

#define NN 100000
#define NE 1600000
#define FDIM 128
#define NGRAPH 128
#define ODIM 16
#define NBKT 391                       // dst-buckets of 256 nodes
#define CAP 4608                       // fixed bucket capacity (mean 4096, sd 64; +8 sigma)
#define SCHUNK 8192                    // edges per k_scat block (512 thr x 16)
#define NSCAT ((NE + SCHUNK - 1) / SCHUNK)  // 196
#define NSTARTB ((NN + 255) / 256)     // 391

typedef __attribute__((ext_vector_type(8))) short short8;
typedef __attribute__((ext_vector_type(8))) unsigned short ushort8;
typedef __attribute__((ext_vector_type(4))) float f32x4;

__device__ __forceinline__ float blo(unsigned int p) { return __uint_as_float(p << 16); }
__device__ __forceinline__ float bhi(unsigned int p) { return __uint_as_float(p & 0xffff0000u); }
__device__ __forceinline__ unsigned short f2b(float f) {
    unsigned int u = __float_as_uint(f);
    unsigned int r = (u + 0x7fffu + ((u >> 16) & 1u)) >> 16;
    return (unsigned short)r;
}
__device__ __forceinline__ unsigned int packbf(float lo, float hi) {
    return (unsigned int)f2b(lo) | ((unsigned int)f2b(hi) << 16);
}

// runtime index-width detect: int64 inputs (values < 2^31) have all-zero odd
// int32 slots; random int32 node ids can't have 64 consecutive zero odd slots.
__device__ __forceinline__ int detect_w(const int* __restrict__ ei) {
    int lane = threadIdx.x & 63;
    int v = ei[2 * lane + 1];
    return (__ballot(v != 0) == 0ULL) ? 1 : 0;
}
__device__ __forceinline__ int ld_idx(const int* __restrict__ p, long long i, int w) {
    return w ? p[2 * i] : p[i];
}

// ---------------- prep: transposes + graph starts + cursors + zero-row ----------------
__global__ void __launch_bounds__(256) k_prep(
    const float* __restrict__ w1, const float* __restrict__ w2,
    unsigned short* __restrict__ wt1, unsigned short* __restrict__ wt2,
    const int* __restrict__ ei, const int* __restrict__ batch,
    int* __restrict__ gstart, int* __restrict__ bcursor,
    unsigned short* __restrict__ xws)
{
    int b = blockIdx.x, t = threadIdx.x;
    if (b < 128) {                       // both 128x128 transposes (fp32 -> bf16)
        int idx = b * 256 + t;           // 0..32767
        int which = idx >> 14, r = idx & 16383;
        int k = r >> 7, j = r & 127;
        const float* w = which ? w2 : w1;
        unsigned short* wt = which ? wt2 : wt1;
        wt[j * 128 + k] = f2b(w[k * 128 + j]);
    } else if (b < 128 + NSTARTB) {      // graph start offsets (batch sorted)
        int w = detect_w(ei);
        int i = (b - 128) * 256 + t;
        if (i < NN) {
            int bb = ld_idx(batch, i, w);
            int prev = (i == 0) ? -1 : ld_idx(batch, i - 1, w);
            for (int g = prev + 1; g <= bb; ++g) gstart[g] = i;
            if (i == NN - 1)
                for (int g = bb + 1; g <= NGRAPH; ++g) gstart[g] = NN;
        }
    } else {                             // cursor init + zero row NN of xws
        int i = (b - 128 - NSTARTB) * 256 + t;
        if (i < NBKT) bcursor[i] = i * CAP;
        if (b == 128 + NSTARTB && t < FDIM) xws[(size_t)NN * FDIM + t] = 0;
    }
}

// ---------------- scatter edges into fixed-stride dst-buckets (RANKED writes) --------
// record = src (17 bits) | (dst & 255) << 17
// Per block: hist -> one global claim per bucket -> per-record LDS rank -> writes land
// as contiguous ~21-record runs per bucket (no per-record random-line RMW).
__global__ void __launch_bounds__(512) k_scat(const int* __restrict__ ei,
                                              int* __restrict__ bcursor,
                                              unsigned int* __restrict__ rec) {
    __shared__ int hist[NBKT];
    __shared__ int gbase[NBKT];
    __shared__ int lcur[NBKT];
    int t = threadIdx.x;
    int w = detect_w(ei);
    for (int i = t; i < NBKT; i += 512) hist[i] = 0;
    __syncthreads();
    long long e0 = (long long)blockIdx.x * SCHUNK;
    unsigned int myrec[16];
    int mybkt[16];
    #pragma unroll
    for (int j = 0; j < 16; ++j) {
        long long e = e0 + j * 512 + t;
        if (e < NE) {
            int s = ld_idx(ei, e, w);
            int d = ld_idx(ei, NE + e, w);
            mybkt[j] = d >> 8;
            myrec[j] = (unsigned int)s | ((unsigned int)(d & 255) << 17);
            atomicAdd(&hist[mybkt[j]], 1);
        } else mybkt[j] = -1;
    }
    __syncthreads();
    for (int i = t; i < NBKT; i += 512) {
        int c = hist[i];
        gbase[i] = c ? atomicAdd(&bcursor[i], c) : 0;
        lcur[i] = 0;
    }
    __syncthreads();
    #pragma unroll
    for (int j = 0; j < 16; ++j) {
        int b = mybkt[j];
        if (b >= 0) {
            int r = atomicAdd(&lcur[b], 1);
            int p = gbase[b] + r;
            if (p < (b + 1) * CAP) rec[p] = myrec[j];   // overflow guard (~never)
        }
    }
}

// ---------------- per-bucket counting sort -> csr + offs + deg + dinv ----------------
__global__ void __launch_bounds__(256) k_bucket(const unsigned int* __restrict__ rec,
                                                const int* __restrict__ bcursor,
                                                int* __restrict__ csr,
                                                int* __restrict__ offs,
                                                int* __restrict__ deg,
                                                float* __restrict__ dinv) {
    __shared__ unsigned int rbuf[CAP];
    __shared__ int srcout[CAP];
    __shared__ int hist[256], scn[256], cur[256];
    int b = blockIdx.x, t = threadIdx.x;
    int base = b * CAP;
    int cnt = bcursor[b] - base;
    if (cnt > CAP) cnt = CAP;
    hist[t] = 0;
    __syncthreads();
    for (int j = t; j < cnt; j += 256) {
        unsigned int r = rec[base + j];
        rbuf[j] = r;
        atomicAdd(&hist[r >> 17], 1);
    }
    __syncthreads();
    int v = hist[t];
    scn[t] = v;
    __syncthreads();
    for (int o = 1; o < 256; o <<= 1) {
        int tv = (t >= o) ? scn[t - o] : 0;
        __syncthreads();
        scn[t] += tv;
        __syncthreads();
    }
    int excl = scn[t] - v;
    cur[t] = excl;
    int node = (b << 8) + t;
    if (node < NN) {
        offs[node] = base + excl;
        deg[node] = v;
        dinv[node] = rsqrtf((float)(v + 1));   // +1 = self loop
    }
    __syncthreads();
    for (int j = t; j < cnt; j += 256) {
        unsigned int r = rbuf[j];
        int p = atomicAdd(&cur[r >> 17], 1);
        srcout[p] = (int)(r & 0x1FFFFu);
    }
    __syncthreads();
    for (int j = t; j < cnt; j += 256) csr[base + j] = srcout[j];
}

// ---------------- GEMM: OUT[v][:] = bf16(dinv[v] * (X[v][:] @ W)) ----------------
#define LWS 136   // padded LDS row stride (bf16 elems)
template <bool BF16IN>
__global__ void __launch_bounds__(256) k_gemm(
    const void* __restrict__ Xv,            // [NN,128] fp32 or bf16
    const unsigned short* __restrict__ WT,  // [128,128] bf16, WT[j][k] = W[k][j]
    const float* __restrict__ dinv,
    unsigned short* __restrict__ OUT)       // [NN,128] bf16, scaled by dinv[row]
{
    __shared__ unsigned short lw[128 * LWS];
    int tid = threadIdx.x;
    for (int it = 0; it < 8; ++it) {
        int vidx = it * 256 + tid;
        int j = vidx >> 4, kc = vidx & 15;
        ushort8 v = *(const ushort8*)(WT + j * 128 + kc * 8);
        *(ushort8*)(&lw[j * LWS + kc * 8]) = v;
    }
    __syncthreads();

    int wave = tid >> 6, lane = tid & 63;
    int quad = lane >> 4, n16 = lane & 15;
    int row0 = (blockIdx.x * 4 + wave) * 16;
    if (row0 >= NN) return;   // NN % 16 == 0

    f32x4 acc[8];
    for (int ct = 0; ct < 8; ++ct) acc[ct] = (f32x4){0.f, 0.f, 0.f, 0.f};

    const int arow = row0 + n16;
    for (int kk = 0; kk < 4; ++kk) {
        short8 a;
        if (BF16IN) {
            a = *(const short8*)((const unsigned short*)Xv + (size_t)arow * 128 + kk * 32 + quad * 8);
        } else {
            const float* ap = (const float*)Xv + (size_t)arow * 128 + kk * 32 + quad * 8;
            float4 a01 = *(const float4*)(ap);
            float4 a23 = *(const float4*)(ap + 4);
            a[0] = (short)f2b(a01.x); a[1] = (short)f2b(a01.y);
            a[2] = (short)f2b(a01.z); a[3] = (short)f2b(a01.w);
            a[4] = (short)f2b(a23.x); a[5] = (short)f2b(a23.y);
            a[6] = (short)f2b(a23.z); a[7] = (short)f2b(a23.w);
        }
        for (int ct = 0; ct < 8; ++ct) {
            short8 b = *(const short8*)(&lw[(ct * 16 + n16) * LWS + kk * 32 + quad * 8]);
            acc[ct] = __builtin_amdgcn_mfma_f32_16x16x32_bf16(a, b, acc[ct], 0, 0, 0);
        }
    }
    // C/D layout: col = lane&15, row = quad*4 + reg
    for (int r = 0; r < 4; ++r) {
        int row = row0 + quad * 4 + r;
        float dv = dinv[row];
        for (int ct = 0; ct < 8; ++ct)
            OUT[(size_t)row * 128 + ct * 16 + n16] = f2b(acc[ct][r] * dv);
    }
}

// ---------------- aggregation: 16 edges in flight per wave, branch-free ----------------
// Lane = (edge slot g 0..3, feature chunk f 0..15). Padded slots gather xws row NN (zeros).
__global__ void __launch_bounds__(256) k_agg(
    const unsigned short* __restrict__ XWS,   // [NN+1,128] bf16, row NN = zeros
    const int* __restrict__ csr,
    const int* __restrict__ offs,
    const int* __restrict__ deg,
    const float* __restrict__ dinv,
    const float* __restrict__ bias,           // 128 fp32
    unsigned short* __restrict__ H)           // [NN,128] bf16
{
    int wave = threadIdx.x >> 6, lane = threadIdx.x & 63;
    int v = blockIdx.x * 4 + wave;             // NN % 4 == 0
    int g = lane >> 4, f = lane & 15;          // edge slot, feature chunk (8 feats)
    int beg = offs[v], end = beg + deg[v];
    float a[8];
    {   // self loop
        uint4 q = *(const uint4*)(XWS + (size_t)v * FDIM + f * 8);
        float m = (g == 0) ? 1.f : 0.f;
        a[0] = m * blo(q.x); a[1] = m * bhi(q.x); a[2] = m * blo(q.y); a[3] = m * bhi(q.y);
        a[4] = m * blo(q.z); a[5] = m * bhi(q.z); a[6] = m * blo(q.w); a[7] = m * bhi(q.w);
    }
    int e1 = end - 1;
    for (int j = beg; j < end; j += 16) {
        int j0 = j + g, j1 = j + 4 + g, j2 = j + 8 + g, j3 = j + 12 + g;
        int i0 = csr[j0 < end ? j0 : e1]; i0 = (j0 < end) ? i0 : NN;
        int i1 = csr[j1 < end ? j1 : e1]; i1 = (j1 < end) ? i1 : NN;
        int i2 = csr[j2 < end ? j2 : e1]; i2 = (j2 < end) ? i2 : NN;
        int i3 = csr[j3 < end ? j3 : e1]; i3 = (j3 < end) ? i3 : NN;
        uint4 q0 = *(const uint4*)(XWS + (size_t)i0 * FDIM + f * 8);
        uint4 q1 = *(const uint4*)(XWS + (size_t)i1 * FDIM + f * 8);
        uint4 q2 = *(const uint4*)(XWS + (size_t)i2 * FDIM + f * 8);
        uint4 q3 = *(const uint4*)(XWS + (size_t)i3 * FDIM + f * 8);
        a[0] += blo(q0.x); a[1] += bhi(q0.x); a[2] += blo(q0.y); a[3] += bhi(q0.y);
        a[4] += blo(q0.z); a[5] += bhi(q0.z); a[6] += blo(q0.w); a[7] += bhi(q0.w);
        a[0] += blo(q1.x); a[1] += bhi(q1.x); a[2] += blo(q1.y); a[3] += bhi(q1.y);
        a[4] += blo(q1.z); a[5] += bhi(q1.z); a[6] += blo(q1.w); a[7] += bhi(q1.w);
        a[0] += blo(q2.x); a[1] += bhi(q2.x); a[2] += blo(q2.y); a[3] += bhi(q2.y);
        a[4] += blo(q2.z); a[5] += bhi(q2.z); a[6] += blo(q2.w); a[7] += bhi(q2.w);
        a[0] += blo(q3.x); a[1] += bhi(q3.x); a[2] += blo(q3.y); a[3] += bhi(q3.y);
        a[4] += blo(q3.z); a[5] += bhi(q3.z); a[6] += blo(q3.w); a[7] += bhi(q3.w);
    }
    #pragma unroll
    for (int i = 0; i < 8; ++i) {
        a[i] += __shfl_xor(a[i], 16);
        a[i] += __shfl_xor(a[i], 32);
    }
    if (g == 0) {
        float dv = dinv[v];
        float4 b0 = *(const float4*)(bias + f * 8);
        float4 b1 = *(const float4*)(bias + f * 8 + 4);
        uint4 o;
        o.x = packbf(fmaxf(fmaf(a[0], dv, b0.x), 0.f), fmaxf(fmaf(a[1], dv, b0.y), 0.f));
        o.y = packbf(fmaxf(fmaf(a[2], dv, b0.z), 0.f), fmaxf(fmaf(a[3], dv, b0.w), 0.f));
        o.z = packbf(fmaxf(fmaf(a[4], dv, b1.x), 0.f), fmaxf(fmaf(a[5], dv, b1.y), 0.f));
        o.w = packbf(fmaxf(fmaf(a[6], dv, b1.z), 0.f), fmaxf(fmaf(a[7], dv, b1.w), 0.f));
        *(uint4*)(H + (size_t)v * FDIM + f * 8) = o;
    }
}

// ---------------- fused global mean pool + classifier ----------------
__global__ void __launch_bounds__(256) k_poolcls(
    const unsigned short* __restrict__ H, const int* __restrict__ gstart,
    const float* __restrict__ wc, const float* __restrict__ bc,
    float* __restrict__ out)
{
    __shared__ float red[512];
    __shared__ float pl[FDIM];
    int g = blockIdx.x;
    int t = threadIdx.x;
    int pair = t & 63;
    int seg = t >> 6;
    int beg = gstart[g], end = gstart[g + 1];
    float a0 = 0.f, a1 = 0.f;
    for (int i = beg + seg; i < end; i += 4) {
        unsigned int q = *(const unsigned int*)(H + (size_t)i * FDIM + 2 * pair);
        a0 += blo(q); a1 += bhi(q);
    }
    red[t] = a0; red[256 + t] = a1;
    __syncthreads();
    if (seg == 0) {
        a0 = red[t] + red[t + 64] + red[t + 128] + red[t + 192];
        a1 = red[256 + t] + red[256 + t + 64] + red[256 + t + 128] + red[256 + t + 192];
        float inv = 1.f / fmaxf((float)(end - beg), 1.f);
        pl[2 * pair] = a0 * inv;
        pl[2 * pair + 1] = a1 * inv;
    }
    __syncthreads();
    int o = t & 15, fs = t >> 4;
    float acc = 0.f;
    #pragma unroll
    for (int k = 0; k < 8; ++k)
        acc += pl[fs * 8 + k] * wc[(fs * 8 + k) * ODIM + o];
    red[t] = acc;
    __syncthreads();
    if (t < 16) {
        float s = bc[t];
        #pragma unroll
        for (int k = 0; k < 16; ++k) s += red[k * 16 + t];
        out[g * ODIM + t] = s;
    }
}

extern "C" void kernel_launch(void* const* d_in, const int* in_sizes, int n_in,
                              void* d_out, int out_size, void* d_ws, size_t ws_size,
                              hipStream_t stream) {
    const float* x   = (const float*)d_in[0];
    const int* ei    = (const int*)d_in[1];
    const int* batch = (const int*)d_in[2];
    const float* w1  = (const float*)d_in[3];
    const float* b1  = (const float*)d_in[4];
    const float* w2  = (const float*)d_in[5];
    const float* b2  = (const float*)d_in[6];
    const float* wc  = (const float*)d_in[7];
    const float* bc  = (const float*)d_in[8];
    float* out = (float*)d_out;

    char* ws = (char*)d_ws;
    size_t off = 0;
    auto alloc = [&](size_t bytes) -> void* {
        off = (off + 255) & ~(size_t)255;
        void* p = ws + off;
        off += bytes;
        return p;
    };
    int*   bcursor = (int*)alloc(NBKT * 4);
    int*   offs    = (int*)alloc(NN * 4);
    int*   deg     = (int*)alloc(NN * 4);
    float* dinv    = (float*)alloc(NN * 4);
    int*   gstart  = (int*)alloc((NGRAPH + 1) * 4);
    unsigned int* rec = (unsigned int*)alloc((size_t)NBKT * CAP * 4);
    int*   csr     = (int*)alloc((size_t)NBKT * CAP * 4 + 256);   // +tail slack
    unsigned short* wt1 = (unsigned short*)alloc(128 * 128 * 2);
    unsigned short* wt2 = (unsigned short*)alloc(128 * 128 * 2);
    unsigned short* xws = (unsigned short*)alloc((size_t)(NN + 1) * FDIM * 2);  // +zero row
    unsigned short* h   = (unsigned short*)alloc((size_t)NN * FDIM * 2);

    k_prep<<<128 + NSTARTB + 2, 256, 0, stream>>>(w1, w2, wt1, wt2, ei, batch, gstart, bcursor, xws);
    k_scat<<<NSCAT, 512, 0, stream>>>(ei, bcursor, rec);
    k_bucket<<<NBKT, 256, 0, stream>>>(rec, bcursor, csr, offs, deg, dinv);

    // layer 1
    k_gemm<false><<<(NN / 16 + 3) / 4, 256, 0, stream>>>(x, wt1, dinv, xws);
    k_agg<<<NN / 4, 256, 0, stream>>>(xws, csr, offs, deg, dinv, b1, h);
    // layer 2
    k_gemm<true><<<(NN / 16 + 3) / 4, 256, 0, stream>>>(h, wt2, dinv, xws);
    k_agg<<<NN / 4, 256, 0, stream>>>(xws, csr, offs, deg, dinv, b2, h);
    // pool + classify (fused)
    k_poolcls<<<NGRAPH, 256, 0, stream>>>(h, gstart, wc, bc, out);
}